// Round 10
// baseline (785.940 us; speedup 1.0000x reference)
//
#include <hip/hip_runtime.h>
#include <math.h>

#define DEV __device__ __forceinline__

static constexpr int BB = 4, SS = 512, LL = 512, HH = 32;
static constexpr float MAXN  = 1.0f - 1e-5f;
static constexpr float MAXN2 = MAXN * MAXN;

DEV float rcpf(float x) { return __builtin_amdgcn_rcpf(x); }
DEV float rsqf(float x) { return __builtin_amdgcn_rsqf(x); }

// ---------------- scalar helpers (prep/label/dist kernels) ----------------
DEV float dot8(const float* a, const float* b) {
  float s0 = a[0]*b[0], s1 = a[1]*b[1], s2 = a[2]*b[2], s3 = a[3]*b[3];
  float s4 = a[4]*b[4], s5 = a[5]*b[5], s6 = a[6]*b[6], s7 = a[7]*b[7];
  return ((s0+s1)+(s2+s3)) + ((s4+s5)+(s6+s7));
}

DEV void load8(float* d, const float* p) {
  float4 a = *(const float4*)p;
  float4 b = *(const float4*)(p + 4);
  d[0]=a.x; d[1]=a.y; d[2]=a.z; d[3]=a.w;
  d[4]=b.x; d[5]=b.y; d[6]=b.z; d[7]=b.w;
}

DEV void store8(float* p, const float* d) {
  *(float4*)p       = make_float4(d[0], d[1], d[2], d[3]);
  *(float4*)(p + 4) = make_float4(d[4], d[5], d[6], d[7]);
}

DEV void project8(float* x) {
  float n2 = dot8(x, x) + 1e-15f;
  if (n2 > MAXN2) {
    float s = MAXN * rsqf(n2);
    #pragma unroll
    for (int i = 0; i < 8; ++i) x[i] *= s;
  }
}

DEV void logmap0_8(float* o, const float* x) {
  float t[8];
  #pragma unroll
  for (int i = 0; i < 8; ++i) t[i] = x[i];
  project8(t);
  float n2 = dot8(t, t) + 1e-15f;
  float rs = rsqf(n2);
  float n  = n2 * rs;
  float c  = fminf(n, 1.0f - 1e-7f);
  float at = 0.34657359f * (__log2f(1.0f + c) - __log2f(1.0f - c));
  float r  = at * rs;
  #pragma unroll
  for (int i = 0; i < 8; ++i) o[i] = t[i] * r;
}

DEV void expmap0_8(float* o, const float* u) {
  float n2 = dot8(u, u) + 1e-15f;
  float rs = rsqf(n2);
  float n  = n2 * rs;
  float e  = __expf(2.0f * n);
  float th = 1.0f - 2.0f * rcpf(e + 1.0f);
  float r  = th * rs;
  #pragma unroll
  for (int i = 0; i < 8; ++i) o[i] = u[i] * r;
  project8(o);
}

DEV void matvec8(float* o, const float* M, const float* u) {
  #pragma unroll
  for (int e = 0; e < 8; ++e) o[e] = dot8(M + 8*e, u);
}

// ---------------- DPP helpers ----------------
template<int CTRL>
DEV float dppf(float x) {
  int xi = __float_as_int(x);
  return __int_as_float(__builtin_amdgcn_update_dpp(xi, xi, CTRL, 0xF, 0xF, true));
}
// xor1=quad_perm 0xB1; xor2=0x4E; xor3=0x1B; xor7=row_half_mirror 0x141;
// half-swap (lane^8 within 16) = row_ror:8 = 0x128.

DEV float grp8sum(float x) {
  x += dppf<0xB1>(x);
  x += dppf<0x4E>(x);
  x += dppf<0x141>(x);
  return x;
}

DEV void red2(float& a, float& b) {
  float t0 = dppf<0xB1>(a),  t1 = dppf<0xB1>(b);  a += t0; b += t1;
  float t2 = dppf<0x4E>(a),  t3 = dppf<0x4E>(b);  a += t2; b += t3;
  float t4 = dppf<0x141>(a), t5 = dppf<0x141>(b); a += t4; b += t5;
}

DEV void red4(float& a, float& b, float& c, float& d) {
  float t0 = dppf<0xB1>(a),  t1 = dppf<0xB1>(b),  t2 = dppf<0xB1>(c),  t3 = dppf<0xB1>(d);
  a += t0; b += t1; c += t2; d += t3;
  float t4 = dppf<0x4E>(a),  t5 = dppf<0x4E>(b),  t6 = dppf<0x4E>(c),  t7 = dppf<0x4E>(d);
  a += t4; b += t5; c += t6; d += t7;
  float t8 = dppf<0x141>(a), t9 = dppf<0x141>(b), ta = dppf<0x141>(c), tb = dppf<0x141>(d);
  a += t8; b += t9; c += ta; d += tb;
}

DEV void red5(float& a, float& b, float& c, float& d, float& e) {
  float t0 = dppf<0xB1>(a),  t1 = dppf<0xB1>(b),  t2 = dppf<0xB1>(c),  t3 = dppf<0xB1>(d),  t4 = dppf<0xB1>(e);
  a += t0; b += t1; c += t2; d += t3; e += t4;
  float u0 = dppf<0x4E>(a),  u1 = dppf<0x4E>(b),  u2 = dppf<0x4E>(c),  u3 = dppf<0x4E>(d),  u4 = dppf<0x4E>(e);
  a += u0; b += u1; c += u2; d += u3; e += u4;
  float v0 = dppf<0x141>(a), v1 = dppf<0x141>(b), v2 = dppf<0x141>(c), v3 = dppf<0x141>(d), v4 = dppf<0x141>(e);
  a += v0; b += v1; c += v2; d += v3; e += v4;
}

#define MV8(w, u0,u1,u2,u3,u4,u5,u6,u7) \
  ((((w[0]*(u0)) + (w[1]*(u1))) + ((w[2]*(u2)) + (w[3]*(u3)))) + \
   (((w[4]*(u4)) + (w[5]*(u5))) + ((w[6]*(u6)) + (w[7]*(u7)))))

// logmap scale: artanh(|x|)/|x| from squared norm (n2 <= MAXN2 guaranteed)
DEV float lgscale(float n2) {
  float n2p = n2 + 1e-15f;
  float rs  = rsqf(n2p);
  float n   = n2p * rs;
  float at  = 0.34657359f * (__log2f(1.0f + n) - __log2f(1.0f - n));
  return at * rs;
}

// One-rcp flattened gate: g2 = (expmap0(v) (+) c) (+) b = P*v + Q*c + R*b.
DEV void gate1(float n2v, float dvc, float dvb,
               float c2, float b2, float b2p1, float cb,
               float& P, float& Q, float& R, float& g2_2) {
  float n2p = n2v + 1e-15f;
  float rsv = rsqf(n2p);
  float nv  = n2p * rsv;
  float ew  = __expf(2.0f * nv);
  float th  = 1.0f - 2.0f * rcpf(ew + 1.0f);
  float asc = th * rsv;                 // a = asc * v
  float a2  = fminf(th * th, MAXN2);
  float xy1 = asc * dvc;
  float ab  = asc * dvb;
  float x2  = 2.0f * xy1;
  float cx1 = 1.0f + x2 + c2;
  float cy1 = 1.0f - a2;
  float D1  = 1.0f + x2 + a2 * c2;
  float N1  = (cx1*a2)*cx1 + (2.0f*cx1)*(cy1*xy1) + (cy1*c2)*cy1;
  float G   = cx1*ab + cy1*cb;
  float C2  = D1*b2p1 + 2.0f*G;
  float D1q = D1*D1;
  float D2  = D1q + 2.0f*(G*D1) + N1*b2;
  float K   = D1q - N1;
  float E   = rcpf(D2);
  float CE  = C2 * E;
  P = (CE * cx1) * asc;
  Q = CE * cy1;
  R = K * E;
  float g2n = (C2*N1)*C2 + 2.0f*(C2*K)*G + (K*b2)*K;
  g2_2 = fminf(g2n * (E*E), MAXN2);
}

// ---------------- input pre-pass: packed layouts for the gru kernel ----------------
// pkV[(t*16 + l16)*2 + {0,1}] = { gate-input comp (az for l16<8, ar for l16>=8), ah comp }
// pkS[t*8 + half*4 .. +3]      = { |cg|^2, <cg,bg>, |ch|^2, <ch,bh> }  per half
__global__ void prep_kernel(const int* __restrict__ x, const float* __restrict__ wemb,
                            const float* __restrict__ Uz, const float* __restrict__ Ur,
                            const float* __restrict__ Uh,
                            const float* __restrict__ bzp, const float* __restrict__ brp,
                            const float* __restrict__ bhp,
                            float* __restrict__ pkV, float* __restrict__ pkS)
{
  int t = blockIdx.x * 256 + threadIdx.x;
  if (t >= BB * SS * HH) return;
  int hh = t & (HH - 1);
  int bs = t >> 5;
  int idx = x[bs];
  float we[8]; load8(we, wemb + ((size_t)idx * HH + hh) * 8);
  project8(we);
  float lx[8]; logmap0_8(lx, we);
  float bz[8], br[8], bh[8];
  load8(bz, bzp); load8(br, brp); load8(bh, bhp);
  float v[8], az[8], ar[8], ah[8];
  matvec8(v, Uz, lx); expmap0_8(az, v);
  matvec8(v, Ur, lx); expmap0_8(ar, v);
  matvec8(v, Uh, lx); expmap0_8(ah, v);
  float cz2 = dot8(az, az), cr2 = dot8(ar, ar), ch2 = dot8(ah, ah);
  float czb = dot8(az, bz), crb = dot8(ar, br), chb = dot8(ah, bh);
  float2* pv = (float2*)(pkV + (size_t)t * 32);
  #pragma unroll
  for (int j = 0; j < 8; ++j) {
    pv[j]     = make_float2(az[j], ah[j]);
    pv[8 + j] = make_float2(ar[j], ah[j]);
  }
  float4* ps = (float4*)(pkS + (size_t)t * 8);
  ps[0] = make_float4(cz2, czb, ch2, chb);
  ps[1] = make_float4(cr2, crb, ch2, chb);
}

// ---------------- label pre-pass ----------------
__global__ void label_kernel(const float* __restrict__ lemb,
                             float* __restrict__ labP, float* __restrict__ l2o)
{
  int t = blockIdx.x * 256 + threadIdx.x;
  if (t >= LL * HH) return;
  float lv[8]; load8(lv, lemb + (size_t)t * 8);
  project8(lv);
  store8(labP + (size_t)t * 8, lv);
  l2o[t] = dot8(lv, lv);
}

// ---------------- GRU scan: 16 lanes/chain, 4 chains/wave, 2 waves/SIMD ----------------
// 4 blocks x 512 threads: 8 waves/block round-robin onto 4 SIMDs -> 2 waves
// co-resident per SIMD fill each other's transcendental-latency stalls.
// Body identical to the verified round-8 kernel (absmax 0.0 at 390 us).
__global__ __launch_bounds__(512, 1) void gru_kernel(
    const float* __restrict__ Wzp, const float* __restrict__ Wrp, const float* __restrict__ Whp,
    const float* __restrict__ bzp, const float* __restrict__ brp, const float* __restrict__ bhp,
    const float* __restrict__ pkV, const float* __restrict__ pkS,
    float* __restrict__ enc, float* __restrict__ e2out)
{
  const int lane = threadIdx.x & 63;     // lane within wave
  const int wid  = threadIdx.x >> 6;     // wave within block (0..7)
  const int d    = lane & 7;             // dim
  const bool hif = (lane & 8) != 0;      // half: 0 -> z gate, 1 -> r gate
  const int cg   = lane >> 4;            // chain within wave (0..3)
  const int l16  = lane & 15;

  // per-lane constants
  float wg[8], wh[8];
  #pragma unroll
  for (int k = 0; k < 8; ++k) {
    wg[k] = (hif ? Wrp : Wzp)[d*8 + (d^k)];
    wh[k] = Whp[d*8 + (d^k)];
  }
  float bgv = (hif ? brp : bzp)[d];
  float bhv = bhp[d];
  float bg2 = grp8sum(bgv*bgv);
  float bh2 = grp8sum(bhv*bhv);
  float bg2p1 = 1.0f + bg2, bh2p1 = 1.0f + bh2;

  const int chain = (blockIdx.x * 8 + wid) * 4 + cg; // 4 blocks x 32 chains
  int soff = (chain >> 5) * SS * HH + (chain & 31);
  int pvo  = soff * 32 + l16 * 2;
  int pso  = soff * 8 + (hif ? 4 : 0);
  int voff = soff * 8 + d;

  float hv = 0.0f, h2 = 0.0f;
  float2 cv = *(const float2*)(pkV + pvo);
  float4 ss = *(const float4*)(pkS + pso);

  #pragma unroll 1
  for (int s = 0; s < SS; ++s) {
    // prefetch next step (at s=511 over-reads into the adjacent ws buffer; unused)
    float2 ncv = *(const float2*)(pkV + (pvo + HH*32));
    float4 nss = *(const float4*)(pkS + (pso + HH*8));

    float cgv = cv.x, chv = cv.y;
    float c2g = ss.x, cbg = ss.y, ch2v = ss.z, chbv = ss.w;

    // ---- step-top: perms + gate matvec on raw hv, h-path pre-products, all
    //      reductions batched; lgscale(h2) runs concurrently.
    float p1 = dppf<0xB1>(hv), p2 = dppf<0x4E>(hv), p3 = dppf<0x1B>(hv), p7 = dppf<0x141>(hv);
    float p4 = dppf<0x1B>(p7), p5 = dppf<0x4E>(p7), p6 = dppf<0xB1>(p7);
    float vg0 = MV8(wg, hv, p1, p2, p3, p4, p5, p6, p7);

    // pre-multiplied h-path matvec coefficients (early, off-path)
    float w0 = wh[0]*hv, w1 = wh[1]*p1, w2 = wh[2]*p2, w3 = wh[3]*p3;
    float w4 = wh[4]*p4, w5 = wh[5]*p5, w6 = wh[6]*p6, w7 = wh[7]*p7;

    float n2g0 = vg0*vg0, dgc0 = vg0*cgv, dgb0 = vg0*bgv;
    float dhch = hv*chv, dhbh = hv*bhv;
    red5(n2g0, dgc0, dgb0, dhch, dhbh);

    float lsc = lgscale(h2);
    float l2s = lsc * lsc;

    // ---- z/r gate (z in half0, r in half1), one-rcp form
    float P, Q, R, g22;
    gate1(n2g0*l2s, dgc0*lsc, dgb0*lsc, c2g, bg2, bg2p1, cbg, P, Q, R, g22);
    float g2 = (P*lsc)*vg0 + Q*cgv + R*bgv;

    // merged sigmoid: sigma(artanh(n)/n * g2), n = |gate vec|
    float g22p = g22 + 1e-15f;
    float rsg  = rsqf(g22p);
    float ng   = g22p * rsg;
    float Lm   = __log2f(1.0f - ng), Lp = __log2f(1.0f + ng);
    float sarg = (0.34657359f * g2) * rsg * (Lm - Lp);
    float gsv  = rcpf(1.0f + __expf(sarg));
    float gsw  = dppf<0x128>(gsv);
    float rv   = hif ? gsv : gsw;
    float zv   = hif ? gsw : gsv;

    // ---- h_tilde path: vh0 = Wh.(rv o hv)  (lsc folded into scalars later)
    float r1 = dppf<0xB1>(rv), r2 = dppf<0x4E>(rv), r3 = dppf<0x1B>(rv), r7 = dppf<0x141>(rv);
    float r4 = dppf<0x1B>(r7), r5 = dppf<0x4E>(r7), r6 = dppf<0xB1>(r7);
    float vh0 = (((w0*rv + w1*r1) + (w2*r2 + w3*r3)) + ((w4*r4 + w5*r5) + (w6*r6 + w7*r7)));

    float n2h0 = vh0*vh0, rhc0 = vh0*chv, rhb0 = vh0*bhv, dhv0 = hv*vh0;
    red4(n2h0, rhc0, rhb0, dhv0);

    float Ph, Qh, Rh, t42;
    gate1(n2h0*l2s, rhc0*lsc, rhb0*lsc, ch2v, bh2, bh2p1, chbv, Ph, Qh, Rh, t42);
    float Phl  = Ph * lsc;
    float t4   = Phl*vh0 + Qh*chv + Rh*bhv;
    float dht4 = Phl*dhv0 + Qh*dhch + Rh*dhbh;     // <h, t4>

    // ---- m = (-h) (+) t4 : scalar chain, concurrent with the vector branch
    float cxm  = 1.0f - 2.0f*dht4 + t42;
    float cym  = 1.0f - h2;                         // == cyf of the final madd
    float denm = 1.0f - 2.0f*dht4 + h2*t42;
    float rdm  = rcpf(denm);
    float m20  = (cxm*h2)*cxm - (2.0f*cxm)*(cym*dht4) + (cym*t42)*cym;
    float m2   = fminf(m20 * (rdm*rdm), MAXN2);
    float lmm  = lgscale(m2);
    float LR   = lmm * rdm;                         // |w| = LR * |wv0|

    // ---- vector branch: wv0 = z o (cym*t4 - cxm*h); reductions overlap m-chain
    float md0 = cym*t4 - cxm*hv;
    float wv0 = zv * md0;
    float n2w0 = wv0*wv0, dhw0 = hv*wv0;
    red2(n2w0, dhw0);
    float n2wp = n2w0 + 1e-15f;
    float rs0  = rsqf(n2wp);
    float nw0  = n2wp * rs0;

    // ---- join: ee = th * rs0 * wv0  (all rescales collapse to W2 = th*rs0)
    float ewt = __expf((2.0f*LR) * nw0);
    float th2 = 1.0f - 2.0f * rcpf(ewt + 1.0f);
    float W2  = th2 * rs0;
    float ee2 = fminf((W2*W2)*n2w0, MAXN2);

    // ---- hn = h (+) ee
    float xyf  = W2 * dhw0;
    float cxf  = 1.0f + 2.0f*xyf + ee2;
    float denf = 1.0f + 2.0f*xyf + h2*ee2;
    float rdf  = rcpf(denf);
    float A    = rdf * cxf;
    float C    = (rdf * cym) * W2;
    float hn   = A*hv + C*wv0;
    float hn2  = fminf(((cxf*h2)*cxf + (2.0f*cxf)*(cym*xyf) + (cym*ee2)*cym) * (rdf*rdf), MAXN2);

    enc[voff]   = hn;     // both halves hold identical values; benign dup write
    e2out[soff] = hn2;

    hv = hn; h2 = hn2;
    cv = ncv; ss = nss;
    pvo += HH*32; pso += HH*8; voff += HH*8; soff += HH;
  }
}

// ---------------- poincare distance sums -> inter [B,L,S], 2x2 per thread ----------------
DEV float pdist(float ee, float ll, float el) {
  float d2  = ee + ll - 2.0f * el;
  float den = fmaxf((1.0f - ee) * (1.0f - ll), 1e-15f);
  float z   = 1.0f + 2.0f * d2 * rcpf(den);
  z = fmaxf(z, 1.0f + 1e-7f);
  return 0.69314718f * __log2f(z + sqrtf(z*z - 1.0f));
}

__global__ __launch_bounds__(256) void dist_kernel(
    const float* __restrict__ enc, const float* __restrict__ e2,
    const float* __restrict__ labP, const float* __restrict__ l2,
    float* __restrict__ inter)
{
  int blk = blockIdx.x;
  int lt = blk & 15, st = (blk >> 4) & 15, b = blk >> 8;
  int li = threadIdx.x & 15, si = threadIdx.x >> 4;
  int s = st * 32 + si * 2, l = lt * 32 + li * 2;

  const float* er0 = enc + ((size_t)b * SS + s) * HH * 8;
  const float* er1 = er0 + HH * 8;
  const float* e20 = e2 + ((size_t)b * SS + s) * HH;
  const float* e21 = e20 + HH;
  const float* lr0 = labP + (size_t)l * HH * 8;
  const float* lr1 = lr0 + HH * 8;
  const float* l20 = l2 + (size_t)l * HH;
  const float* l21 = l20 + HH;

  float a00 = 0.f, a01 = 0.f, a10 = 0.f, a11 = 0.f;
  #pragma unroll 2
  for (int hh = 0; hh < HH; ++hh) {
    float ev0[8], ev1[8], lv0[8], lv1[8];
    load8(ev0, er0 + hh * 8); load8(ev1, er1 + hh * 8);
    load8(lv0, lr0 + hh * 8); load8(lv1, lr1 + hh * 8);
    float x00 = dot8(ev0, lv0), x01 = dot8(ev0, lv1);
    float x10 = dot8(ev1, lv0), x11 = dot8(ev1, lv1);
    float e0v = e20[hh], e1v = e21[hh], l0v = l20[hh], l1v = l21[hh];
    a00 += pdist(e0v, l0v, x00);
    a01 += pdist(e0v, l1v, x01);
    a10 += pdist(e1v, l0v, x10);
    a11 += pdist(e1v, l1v, x11);
  }
  float* o0 = inter + ((size_t)b * LL + l) * SS + s;
  o0[0] = a00; o0[1] = a10;
  o0[SS] = a01; o0[SS + 1] = a11;
}

// ---------------- MLP stage 1: h = relu(inter @ W1^T + b1) ----------------
__global__ __launch_bounds__(256) void mlp1_kernel(
    const float* __restrict__ inter, const float* __restrict__ W1,
    const float* __restrict__ b1, float* __restrict__ hbuf)
{
  __shared__ float As[32][33];
  __shared__ float Bs[32][33];
  int t = threadIdx.x;
  int nt = blockIdx.x & 7, mt = blockIdx.x >> 3;
  int row0 = mt * 32, j0 = nt * 32;
  int li = t >> 4, ji = t & 15;
  float acc00 = 0.f, acc01 = 0.f, acc10 = 0.f, acc11 = 0.f;

  for (int k0 = 0; k0 < 512; k0 += 32) {
    __syncthreads();
    {
      int l = t >> 3, kk = (t & 7) * 4;
      float4 v = *(const float4*)(inter + (size_t)(row0 + l) * 512 + k0 + kk);
      As[l][kk] = v.x; As[l][kk+1] = v.y; As[l][kk+2] = v.z; As[l][kk+3] = v.w;
      float4 w = *(const float4*)(W1 + (size_t)(j0 + l) * 512 + k0 + kk);
      Bs[kk][l] = w.x; Bs[kk+1][l] = w.y; Bs[kk+2][l] = w.z; Bs[kk+3][l] = w.w;
    }
    __syncthreads();
    #pragma unroll
    for (int kk = 0; kk < 32; ++kk) {
      float a0 = As[li][kk],  a1 = As[li + 16][kk];
      float b0 = Bs[kk][ji],  b1v = Bs[kk][ji + 16];
      acc00 = fmaf(a0, b0, acc00);
      acc01 = fmaf(a0, b1v, acc01);
      acc10 = fmaf(a1, b0, acc10);
      acc11 = fmaf(a1, b1v, acc11);
    }
  }
  float bj0 = b1[j0 + ji], bj1 = b1[j0 + ji + 16];
  hbuf[(size_t)(row0 + li)      * 256 + j0 + ji]      = fmaxf(acc00 + bj0, 0.f);
  hbuf[(size_t)(row0 + li)      * 256 + j0 + ji + 16] = fmaxf(acc01 + bj1, 0.f);
  hbuf[(size_t)(row0 + li + 16) * 256 + j0 + ji]      = fmaxf(acc10 + bj0, 0.f);
  hbuf[(size_t)(row0 + li + 16) * 256 + j0 + ji + 16] = fmaxf(acc11 + bj1, 0.f);
}

// ---------------- MLP stage 2: out = h @ W2^T + b2 ----------------
__global__ void mlp2_kernel(const float* __restrict__ hbuf, const float* __restrict__ W2,
                            const float* __restrict__ b2, float* __restrict__ out)
{
  int t = threadIdx.x;
  int row = blockIdx.x * 4 + (t >> 6);
  int lane = t & 63;
  float v = 0.f;
  #pragma unroll
  for (int p = 0; p < 4; ++p) {
    int j = lane + p * 64;
    v = fmaf(hbuf[(size_t)row * 256 + j], W2[j], v);
  }
  #pragma unroll
  for (int off = 32; off > 0; off >>= 1) v += __shfl_xor(v, off);
  if (lane == 0) out[row] = v + b2[0];
}

extern "C" void kernel_launch(void* const* d_in, const int* in_sizes, int n_in,
                              void* d_out, int out_size, void* d_ws, size_t ws_size,
                              hipStream_t stream) {
  (void)in_sizes; (void)n_in; (void)out_size; (void)ws_size;
  const int*   x    = (const int*)d_in[0];
  const float* wemb = (const float*)d_in[1];
  const float* lemb = (const float*)d_in[2];
  const float* Wz = (const float*)d_in[3];
  const float* Wr = (const float*)d_in[4];
  const float* Wh = (const float*)d_in[5];
  const float* Uz = (const float*)d_in[6];
  const float* Ur = (const float*)d_in[7];
  const float* Uh = (const float*)d_in[8];
  const float* bz = (const float*)d_in[9];
  const float* br = (const float*)d_in[10];
  const float* bh = (const float*)d_in[11];
  const float* W1 = (const float*)d_in[12];
  const float* b1 = (const float*)d_in[13];
  const float* W2 = (const float*)d_in[14];
  const float* b2 = (const float*)d_in[15];
  float* out = (float*)d_out;

  float* p = (float*)d_ws;
  const size_t NBSH  = (size_t)BB * SS * HH;       // 65536
  // NOTE: buffer ORDER matters — gru prefetch over-reads one step past pkV/pkS
  // ends; those reads land in the next buffer (mapped workspace), values unused.
  float* pkV  = p; p += NBSH * 32;                 // 2097152
  float* pkS  = p; p += NBSH * 8;                  // 524288
  float* enc  = p; p += NBSH * 8;                  // 524288
  float* e2   = p; p += NBSH;                      // 65536
  float* labP = p; p += (size_t)LL * HH * 8;       // 131072
  float* l2   = p; p += (size_t)LL * HH;           // 16384
  float* inter= p; p += (size_t)BB * LL * SS;      // 1048576
  float* hbuf = p; p += (size_t)BB * LL * 256;     // 524288

  prep_kernel <<<(BB * SS * HH) / 256, 256, 0, stream>>>(x, wemb, Uz, Ur, Uh, bz, br, bh,
                                                         pkV, pkS);
  label_kernel<<<(LL * HH) / 256, 256, 0, stream>>>(lemb, labP, l2);
  gru_kernel  <<<4, 512, 0, stream>>>(Wz, Wr, Wh, bz, br, bh, pkV, pkS, enc, e2);
  dist_kernel <<<BB * (SS / 32) * (LL / 32), 256, 0, stream>>>(enc, e2, labP, l2, inter);
  mlp1_kernel <<<512, 256, 0, stream>>>(inter, W1, b1, hbuf);
  mlp2_kernel <<<512, 256, 0, stream>>>(hbuf, W2, b2, out);
}

// Round 11
// 518.389 us; speedup vs baseline: 1.5161x; 1.5161x over previous
//
#include <hip/hip_runtime.h>
#include <math.h>

#define DEV __device__ __forceinline__

static constexpr int BB = 4, SS = 512, LL = 512, HH = 32;
static constexpr float MAXN  = 1.0f - 1e-5f;
static constexpr float MAXN2 = MAXN * MAXN;

DEV float rcpf(float x) { return __builtin_amdgcn_rcpf(x); }
DEV float rsqf(float x) { return __builtin_amdgcn_rsqf(x); }

// ---------------- scalar helpers (prep/label/dist kernels) ----------------
DEV float dot8(const float* a, const float* b) {
  float s0 = a[0]*b[0], s1 = a[1]*b[1], s2 = a[2]*b[2], s3 = a[3]*b[3];
  float s4 = a[4]*b[4], s5 = a[5]*b[5], s6 = a[6]*b[6], s7 = a[7]*b[7];
  return ((s0+s1)+(s2+s3)) + ((s4+s5)+(s6+s7));
}

DEV void load8(float* d, const float* p) {
  float4 a = *(const float4*)p;
  float4 b = *(const float4*)(p + 4);
  d[0]=a.x; d[1]=a.y; d[2]=a.z; d[3]=a.w;
  d[4]=b.x; d[5]=b.y; d[6]=b.z; d[7]=b.w;
}

DEV void store8(float* p, const float* d) {
  *(float4*)p       = make_float4(d[0], d[1], d[2], d[3]);
  *(float4*)(p + 4) = make_float4(d[4], d[5], d[6], d[7]);
}

DEV void project8(float* x) {
  float n2 = dot8(x, x) + 1e-15f;
  if (n2 > MAXN2) {
    float s = MAXN * rsqf(n2);
    #pragma unroll
    for (int i = 0; i < 8; ++i) x[i] *= s;
  }
}

DEV void logmap0_8(float* o, const float* x) {
  float t[8];
  #pragma unroll
  for (int i = 0; i < 8; ++i) t[i] = x[i];
  project8(t);
  float n2 = dot8(t, t) + 1e-15f;
  float rs = rsqf(n2);
  float n  = n2 * rs;
  float c  = fminf(n, 1.0f - 1e-7f);
  float at = 0.34657359f * (__log2f(1.0f + c) - __log2f(1.0f - c));
  float r  = at * rs;
  #pragma unroll
  for (int i = 0; i < 8; ++i) o[i] = t[i] * r;
}

DEV void expmap0_8(float* o, const float* u) {
  float n2 = dot8(u, u) + 1e-15f;
  float rs = rsqf(n2);
  float n  = n2 * rs;
  float e  = __expf(2.0f * n);
  float th = 1.0f - 2.0f * rcpf(e + 1.0f);
  float r  = th * rs;
  #pragma unroll
  for (int i = 0; i < 8; ++i) o[i] = u[i] * r;
  project8(o);
}

DEV void matvec8(float* o, const float* M, const float* u) {
  #pragma unroll
  for (int e = 0; e < 8; ++e) o[e] = dot8(M + 8*e, u);
}

// ---------------- DPP helpers ----------------
template<int CTRL>
DEV float dppf(float x) {
  int xi = __float_as_int(x);
  return __int_as_float(__builtin_amdgcn_update_dpp(xi, xi, CTRL, 0xF, 0xF, true));
}
// xor1=quad_perm 0xB1; xor2=0x4E; xor3=0x1B; xor7=row_half_mirror 0x141;
// half-swap (lane^8 within 16) = row_ror:8 = 0x128.

DEV float grp8sum(float x) {
  x += dppf<0xB1>(x);
  x += dppf<0x4E>(x);
  x += dppf<0x141>(x);
  return x;
}

DEV void red2(float& a, float& b) {
  float t0 = dppf<0xB1>(a),  t1 = dppf<0xB1>(b);  a += t0; b += t1;
  float t2 = dppf<0x4E>(a),  t3 = dppf<0x4E>(b);  a += t2; b += t3;
  float t4 = dppf<0x141>(a), t5 = dppf<0x141>(b); a += t4; b += t5;
}

DEV void red4(float& a, float& b, float& c, float& d) {
  float t0 = dppf<0xB1>(a),  t1 = dppf<0xB1>(b),  t2 = dppf<0xB1>(c),  t3 = dppf<0xB1>(d);
  a += t0; b += t1; c += t2; d += t3;
  float t4 = dppf<0x4E>(a),  t5 = dppf<0x4E>(b),  t6 = dppf<0x4E>(c),  t7 = dppf<0x4E>(d);
  a += t4; b += t5; c += t6; d += t7;
  float t8 = dppf<0x141>(a), t9 = dppf<0x141>(b), ta = dppf<0x141>(c), tb = dppf<0x141>(d);
  a += t8; b += t9; c += ta; d += tb;
}

DEV void red5(float& a, float& b, float& c, float& d, float& e) {
  float t0 = dppf<0xB1>(a),  t1 = dppf<0xB1>(b),  t2 = dppf<0xB1>(c),  t3 = dppf<0xB1>(d),  t4 = dppf<0xB1>(e);
  a += t0; b += t1; c += t2; d += t3; e += t4;
  float u0 = dppf<0x4E>(a),  u1 = dppf<0x4E>(b),  u2 = dppf<0x4E>(c),  u3 = dppf<0x4E>(d),  u4 = dppf<0x4E>(e);
  a += u0; b += u1; c += u2; d += u3; e += u4;
  float v0 = dppf<0x141>(a), v1 = dppf<0x141>(b), v2 = dppf<0x141>(c), v3 = dppf<0x141>(d), v4 = dppf<0x141>(e);
  a += v0; b += v1; c += v2; d += v3; e += v4;
}

#define MV8(w, u0,u1,u2,u3,u4,u5,u6,u7) \
  ((((w[0]*(u0)) + (w[1]*(u1))) + ((w[2]*(u2)) + (w[3]*(u3)))) + \
   (((w[4]*(u4)) + (w[5]*(u5))) + ((w[6]*(u6)) + (w[7]*(u7)))))

// logmap scale: artanh(|x|)/|x| from squared norm (n2 <= MAXN2 guaranteed)
DEV float lgscale(float n2) {
  float n2p = n2 + 1e-15f;
  float rs  = rsqf(n2p);
  float n   = n2p * rs;
  float at  = 0.34657359f * (__log2f(1.0f + n) - __log2f(1.0f - n));
  return at * rs;
}

// One-rcp flattened gate: g2 = (expmap0(v) (+) c) (+) b = P*v + Q*c + R*b.
DEV void gate1(float n2v, float dvc, float dvb,
               float c2, float b2, float b2p1, float cb,
               float& P, float& Q, float& R, float& g2_2) {
  float n2p = n2v + 1e-15f;
  float rsv = rsqf(n2p);
  float nv  = n2p * rsv;
  float ew  = __expf(2.0f * nv);
  float th  = 1.0f - 2.0f * rcpf(ew + 1.0f);
  float asc = th * rsv;                 // a = asc * v
  float a2  = fminf(th * th, MAXN2);
  float xy1 = asc * dvc;
  float ab  = asc * dvb;
  float x2  = 2.0f * xy1;
  float cx1 = 1.0f + x2 + c2;
  float cy1 = 1.0f - a2;
  float D1  = 1.0f + x2 + a2 * c2;
  float N1  = (cx1*a2)*cx1 + (2.0f*cx1)*(cy1*xy1) + (cy1*c2)*cy1;
  float G   = cx1*ab + cy1*cb;
  float C2  = D1*b2p1 + 2.0f*G;
  float D1q = D1*D1;
  float D2  = D1q + 2.0f*(G*D1) + N1*b2;
  float K   = D1q - N1;
  float E   = rcpf(D2);
  float CE  = C2 * E;
  P = (CE * cx1) * asc;
  Q = CE * cy1;
  R = K * E;
  float g2n = (C2*N1)*C2 + 2.0f*(C2*K)*G + (K*b2)*K;
  g2_2 = fminf(g2n * (E*E), MAXN2);
}

// ---------------- input pre-pass: packed layouts for the gru kernel ----------------
// pkV[(t*16 + l16)*2 + {0,1}] = { gate-input comp (az for l16<8, ar for l16>=8), ah comp }
// pkS[t*8 + half*4 .. +3]      = { |cg|^2, <cg,bg>, |ch|^2, <ch,bh> }  per half
__global__ void prep_kernel(const int* __restrict__ x, const float* __restrict__ wemb,
                            const float* __restrict__ Uz, const float* __restrict__ Ur,
                            const float* __restrict__ Uh,
                            const float* __restrict__ bzp, const float* __restrict__ brp,
                            const float* __restrict__ bhp,
                            float* __restrict__ pkV, float* __restrict__ pkS)
{
  int t = blockIdx.x * 256 + threadIdx.x;
  if (t >= BB * SS * HH) return;
  int hh = t & (HH - 1);
  int bs = t >> 5;
  int idx = x[bs];
  float we[8]; load8(we, wemb + ((size_t)idx * HH + hh) * 8);
  project8(we);
  float lx[8]; logmap0_8(lx, we);
  float bz[8], br[8], bh[8];
  load8(bz, bzp); load8(br, brp); load8(bh, bhp);
  float v[8], az[8], ar[8], ah[8];
  matvec8(v, Uz, lx); expmap0_8(az, v);
  matvec8(v, Ur, lx); expmap0_8(ar, v);
  matvec8(v, Uh, lx); expmap0_8(ah, v);
  float cz2 = dot8(az, az), cr2 = dot8(ar, ar), ch2 = dot8(ah, ah);
  float czb = dot8(az, bz), crb = dot8(ar, br), chb = dot8(ah, bh);
  float2* pv = (float2*)(pkV + (size_t)t * 32);
  #pragma unroll
  for (int j = 0; j < 8; ++j) {
    pv[j]     = make_float2(az[j], ah[j]);
    pv[8 + j] = make_float2(ar[j], ah[j]);
  }
  float4* ps = (float4*)(pkS + (size_t)t * 8);
  ps[0] = make_float4(cz2, czb, ch2, chb);
  ps[1] = make_float4(cr2, crb, ch2, chb);
}

// ---------------- label pre-pass ----------------
__global__ void label_kernel(const float* __restrict__ lemb,
                             float* __restrict__ labP, float* __restrict__ l2o)
{
  int t = blockIdx.x * 256 + threadIdx.x;
  if (t >= LL * HH) return;
  float lv[8]; load8(lv, lemb + (size_t)t * 8);
  project8(lv);
  store8(labP + (size_t)t * 8, lv);
  l2o[t] = dot8(lv, lv);
}

// ---------------- GRU scan: 16 lanes/chain, 4 chains/wave, 1 wave/SIMD ----------------
// Round-8 verified config (390 us, absmax 0.0): wall = per-wave issue (74%) +
// transcendental stall (26%); multi-wave and in-stream interleave both measured
// worse (r5/r6/r9/r10). Body = r8 + exact hn2 simplification.
__global__ __launch_bounds__(64, 1) void gru_kernel(
    const float* __restrict__ Wzp, const float* __restrict__ Wrp, const float* __restrict__ Whp,
    const float* __restrict__ bzp, const float* __restrict__ brp, const float* __restrict__ bhp,
    const float* __restrict__ pkV, const float* __restrict__ pkS,
    float* __restrict__ enc, float* __restrict__ e2out)
{
  const int lane = threadIdx.x;          // 0..63
  const int d    = lane & 7;             // dim
  const bool hif = (lane & 8) != 0;      // half: 0 -> z gate, 1 -> r gate
  const int cg   = lane >> 4;            // chain within wave (0..3)
  const int l16  = lane & 15;

  // per-lane constants
  float wg[8], wh[8];
  #pragma unroll
  for (int k = 0; k < 8; ++k) {
    wg[k] = (hif ? Wrp : Wzp)[d*8 + (d^k)];
    wh[k] = Whp[d*8 + (d^k)];
  }
  float bgv = (hif ? brp : bzp)[d];
  float bhv = bhp[d];
  float bg2 = grp8sum(bgv*bgv);
  float bh2 = grp8sum(bhv*bhv);
  float bg2p1 = 1.0f + bg2, bh2p1 = 1.0f + bh2;

  const int chain = blockIdx.x * 4 + cg; // 32 blocks x 4 chains
  int soff = (chain >> 5) * SS * HH + (chain & 31);
  int pvo  = soff * 32 + l16 * 2;
  int pso  = soff * 8 + (hif ? 4 : 0);
  int voff = soff * 8 + d;

  float hv = 0.0f, h2 = 0.0f;
  float2 cv = *(const float2*)(pkV + pvo);
  float4 ss = *(const float4*)(pkS + pso);

  #pragma unroll 1
  for (int s = 0; s < SS; ++s) {
    // prefetch next step (at s=511 over-reads into the adjacent ws buffer; unused)
    float2 ncv = *(const float2*)(pkV + (pvo + HH*32));
    float4 nss = *(const float4*)(pkS + (pso + HH*8));

    float cgv = cv.x, chv = cv.y;
    float c2g = ss.x, cbg = ss.y, ch2v = ss.z, chbv = ss.w;

    // ---- step-top: perms + gate matvec on raw hv, h-path pre-products, all
    //      reductions batched; lgscale(h2) runs concurrently.
    float p1 = dppf<0xB1>(hv), p2 = dppf<0x4E>(hv), p3 = dppf<0x1B>(hv), p7 = dppf<0x141>(hv);
    float p4 = dppf<0x1B>(p7), p5 = dppf<0x4E>(p7), p6 = dppf<0xB1>(p7);
    float vg0 = MV8(wg, hv, p1, p2, p3, p4, p5, p6, p7);

    // pre-multiplied h-path matvec coefficients (early, off-path)
    float w0 = wh[0]*hv, w1 = wh[1]*p1, w2 = wh[2]*p2, w3 = wh[3]*p3;
    float w4 = wh[4]*p4, w5 = wh[5]*p5, w6 = wh[6]*p6, w7 = wh[7]*p7;

    float n2g0 = vg0*vg0, dgc0 = vg0*cgv, dgb0 = vg0*bgv;
    float dhch = hv*chv, dhbh = hv*bhv;
    red5(n2g0, dgc0, dgb0, dhch, dhbh);

    float lsc = lgscale(h2);
    float l2s = lsc * lsc;

    // ---- z/r gate (z in half0, r in half1), one-rcp form
    float P, Q, R, g22;
    gate1(n2g0*l2s, dgc0*lsc, dgb0*lsc, c2g, bg2, bg2p1, cbg, P, Q, R, g22);
    float g2 = (P*lsc)*vg0 + Q*cgv + R*bgv;

    // merged sigmoid: sigma(artanh(n)/n * g2), n = |gate vec|
    float g22p = g22 + 1e-15f;
    float rsg  = rsqf(g22p);
    float ng   = g22p * rsg;
    float Lm   = __log2f(1.0f - ng), Lp = __log2f(1.0f + ng);
    float sarg = (0.34657359f * g2) * rsg * (Lm - Lp);
    float gsv  = rcpf(1.0f + __expf(sarg));
    float gsw  = dppf<0x128>(gsv);
    float rv   = hif ? gsv : gsw;
    float zv   = hif ? gsw : gsv;

    // ---- h_tilde path: vh0 = Wh.(rv o hv)  (lsc folded into scalars later)
    float r1 = dppf<0xB1>(rv), r2 = dppf<0x4E>(rv), r3 = dppf<0x1B>(rv), r7 = dppf<0x141>(rv);
    float r4 = dppf<0x1B>(r7), r5 = dppf<0x4E>(r7), r6 = dppf<0xB1>(r7);
    float vh0 = (((w0*rv + w1*r1) + (w2*r2 + w3*r3)) + ((w4*r4 + w5*r5) + (w6*r6 + w7*r7)));

    float n2h0 = vh0*vh0, rhc0 = vh0*chv, rhb0 = vh0*bhv, dhv0 = hv*vh0;
    red4(n2h0, rhc0, rhb0, dhv0);

    float Ph, Qh, Rh, t42;
    gate1(n2h0*l2s, rhc0*lsc, rhb0*lsc, ch2v, bh2, bh2p1, chbv, Ph, Qh, Rh, t42);
    float Phl  = Ph * lsc;
    float t4   = Phl*vh0 + Qh*chv + Rh*bhv;
    float dht4 = Phl*dhv0 + Qh*dhch + Rh*dhbh;     // <h, t4>

    // ---- m = (-h) (+) t4 : scalar chain, concurrent with the vector branch
    float cxm  = 1.0f - 2.0f*dht4 + t42;
    float cym  = 1.0f - h2;                         // == cyf of the final madd
    float denm = 1.0f - 2.0f*dht4 + h2*t42;
    float rdm  = rcpf(denm);
    float m20  = (cxm*h2)*cxm - (2.0f*cxm)*(cym*dht4) + (cym*t42)*cym;
    float m2   = fminf(m20 * (rdm*rdm), MAXN2);
    float lmm  = lgscale(m2);
    float LR   = lmm * rdm;                         // |w| = LR * |wv0|

    // ---- vector branch: wv0 = z o (cym*t4 - cxm*h); reductions overlap m-chain
    float md0 = cym*t4 - cxm*hv;
    float wv0 = zv * md0;
    float n2w0 = wv0*wv0, dhw0 = hv*wv0;
    red2(n2w0, dhw0);
    float n2wp = n2w0 + 1e-15f;
    float rs0  = rsqf(n2wp);
    float nw0  = n2wp * rs0;

    // ---- join: ee = th * rs0 * wv0  (all rescales collapse to W2 = th*rs0)
    float ewt = __expf((2.0f*LR) * nw0);
    float th2 = 1.0f - 2.0f * rcpf(ewt + 1.0f);
    float W2  = th2 * rs0;
    float ee2 = fminf((W2*W2)*n2w0, MAXN2);

    // ---- hn = h (+) ee ;  hn2 directly from A,C scalars (exact identity)
    float xyf  = W2 * dhw0;
    float cxf  = 1.0f + 2.0f*xyf + ee2;
    float denf = 1.0f + 2.0f*xyf + h2*ee2;
    float rdf  = rcpf(denf);
    float A    = rdf * cxf;
    float C    = (rdf * cym) * W2;
    float hn   = A*hv + C*wv0;
    float hn2  = fminf((A*h2)*A + (2.0f*A)*(C*dhw0) + (C*n2w0)*C, MAXN2);

    enc[voff]   = hn;     // both halves hold identical values; benign dup write
    e2out[soff] = hn2;

    hv = hn; h2 = hn2;
    cv = ncv; ss = nss;
    pvo += HH*32; pso += HH*8; voff += HH*8; soff += HH;
  }
}

// ---------------- poincare distance sums -> inter [B,L,S], 2x2 per thread ----------------
DEV float pdist(float ee, float ll, float el) {
  float d2  = ee + ll - 2.0f * el;
  float den = fmaxf((1.0f - ee) * (1.0f - ll), 1e-15f);
  float z   = 1.0f + 2.0f * d2 * rcpf(den);
  z = fmaxf(z, 1.0f + 1e-7f);
  return 0.69314718f * __log2f(z + sqrtf(z*z - 1.0f));
}

__global__ __launch_bounds__(256) void dist_kernel(
    const float* __restrict__ enc, const float* __restrict__ e2,
    const float* __restrict__ labP, const float* __restrict__ l2,
    float* __restrict__ inter)
{
  int blk = blockIdx.x;
  int lt = blk & 15, st = (blk >> 4) & 15, b = blk >> 8;
  int li = threadIdx.x & 15, si = threadIdx.x >> 4;
  int s = st * 32 + si * 2, l = lt * 32 + li * 2;

  const float* er0 = enc + ((size_t)b * SS + s) * HH * 8;
  const float* er1 = er0 + HH * 8;
  const float* e20 = e2 + ((size_t)b * SS + s) * HH;
  const float* e21 = e20 + HH;
  const float* lr0 = labP + (size_t)l * HH * 8;
  const float* lr1 = lr0 + HH * 8;
  const float* l20 = l2 + (size_t)l * HH;
  const float* l21 = l20 + HH;

  float a00 = 0.f, a01 = 0.f, a10 = 0.f, a11 = 0.f;
  #pragma unroll 2
  for (int hh = 0; hh < HH; ++hh) {
    float ev0[8], ev1[8], lv0[8], lv1[8];
    load8(ev0, er0 + hh * 8); load8(ev1, er1 + hh * 8);
    load8(lv0, lr0 + hh * 8); load8(lv1, lr1 + hh * 8);
    float x00 = dot8(ev0, lv0), x01 = dot8(ev0, lv1);
    float x10 = dot8(ev1, lv0), x11 = dot8(ev1, lv1);
    float e0v = e20[hh], e1v = e21[hh], l0v = l20[hh], l1v = l21[hh];
    a00 += pdist(e0v, l0v, x00);
    a01 += pdist(e0v, l1v, x01);
    a10 += pdist(e1v, l0v, x10);
    a11 += pdist(e1v, l1v, x11);
  }
  float* o0 = inter + ((size_t)b * LL + l) * SS + s;
  o0[0] = a00; o0[1] = a10;
  o0[SS] = a01; o0[SS + 1] = a11;
}

// ---------------- MLP stage 1: h = relu(inter @ W1^T + b1) ----------------
__global__ __launch_bounds__(256) void mlp1_kernel(
    const float* __restrict__ inter, const float* __restrict__ W1,
    const float* __restrict__ b1, float* __restrict__ hbuf)
{
  __shared__ float As[32][33];
  __shared__ float Bs[32][33];
  int t = threadIdx.x;
  int nt = blockIdx.x & 7, mt = blockIdx.x >> 3;
  int row0 = mt * 32, j0 = nt * 32;
  int li = t >> 4, ji = t & 15;
  float acc00 = 0.f, acc01 = 0.f, acc10 = 0.f, acc11 = 0.f;

  for (int k0 = 0; k0 < 512; k0 += 32) {
    __syncthreads();
    {
      int l = t >> 3, kk = (t & 7) * 4;
      float4 v = *(const float4*)(inter + (size_t)(row0 + l) * 512 + k0 + kk);
      As[l][kk] = v.x; As[l][kk+1] = v.y; As[l][kk+2] = v.z; As[l][kk+3] = v.w;
      float4 w = *(const float4*)(W1 + (size_t)(j0 + l) * 512 + k0 + kk);
      Bs[kk][l] = w.x; Bs[kk+1][l] = w.y; Bs[kk+2][l] = w.z; Bs[kk+3][l] = w.w;
    }
    __syncthreads();
    #pragma unroll
    for (int kk = 0; kk < 32; ++kk) {
      float a0 = As[li][kk],  a1 = As[li + 16][kk];
      float b0 = Bs[kk][ji],  b1v = Bs[kk][ji + 16];
      acc00 = fmaf(a0, b0, acc00);
      acc01 = fmaf(a0, b1v, acc01);
      acc10 = fmaf(a1, b0, acc10);
      acc11 = fmaf(a1, b1v, acc11);
    }
  }
  float bj0 = b1[j0 + ji], bj1 = b1[j0 + ji + 16];
  hbuf[(size_t)(row0 + li)      * 256 + j0 + ji]      = fmaxf(acc00 + bj0, 0.f);
  hbuf[(size_t)(row0 + li)      * 256 + j0 + ji + 16] = fmaxf(acc01 + bj1, 0.f);
  hbuf[(size_t)(row0 + li + 16) * 256 + j0 + ji]      = fmaxf(acc10 + bj0, 0.f);
  hbuf[(size_t)(row0 + li + 16) * 256 + j0 + ji + 16] = fmaxf(acc11 + bj1, 0.f);
}

// ---------------- MLP stage 2: out = h @ W2^T + b2 ----------------
__global__ void mlp2_kernel(const float* __restrict__ hbuf, const float* __restrict__ W2,
                            const float* __restrict__ b2, float* __restrict__ out)
{
  int t = threadIdx.x;
  int row = blockIdx.x * 4 + (t >> 6);
  int lane = t & 63;
  float v = 0.f;
  #pragma unroll
  for (int p = 0; p < 4; ++p) {
    int j = lane + p * 64;
    v = fmaf(hbuf[(size_t)row * 256 + j], W2[j], v);
  }
  #pragma unroll
  for (int off = 32; off > 0; off >>= 1) v += __shfl_xor(v, off);
  if (lane == 0) out[row] = v + b2[0];
}

extern "C" void kernel_launch(void* const* d_in, const int* in_sizes, int n_in,
                              void* d_out, int out_size, void* d_ws, size_t ws_size,
                              hipStream_t stream) {
  (void)in_sizes; (void)n_in; (void)out_size; (void)ws_size;
  const int*   x    = (const int*)d_in[0];
  const float* wemb = (const float*)d_in[1];
  const float* lemb = (const float*)d_in[2];
  const float* Wz = (const float*)d_in[3];
  const float* Wr = (const float*)d_in[4];
  const float* Wh = (const float*)d_in[5];
  const float* Uz = (const float*)d_in[6];
  const float* Ur = (const float*)d_in[7];
  const float* Uh = (const float*)d_in[8];
  const float* bz = (const float*)d_in[9];
  const float* br = (const float*)d_in[10];
  const float* bh = (const float*)d_in[11];
  const float* W1 = (const float*)d_in[12];
  const float* b1 = (const float*)d_in[13];
  const float* W2 = (const float*)d_in[14];
  const float* b2 = (const float*)d_in[15];
  float* out = (float*)d_out;

  float* p = (float*)d_ws;
  const size_t NBSH  = (size_t)BB * SS * HH;       // 65536
  // NOTE: buffer ORDER matters — gru prefetch over-reads one step past pkV/pkS
  // ends; those reads land in the next buffer (mapped workspace), values unused.
  float* pkV  = p; p += NBSH * 32;                 // 2097152
  float* pkS  = p; p += NBSH * 8;                  // 524288
  float* enc  = p; p += NBSH * 8;                  // 524288
  float* e2   = p; p += NBSH;                      // 65536
  float* labP = p; p += (size_t)LL * HH * 8;       // 131072
  float* l2   = p; p += (size_t)LL * HH;           // 16384
  float* inter= p; p += (size_t)BB * LL * SS;      // 1048576
  float* hbuf = p; p += (size_t)BB * LL * 256;     // 524288

  prep_kernel <<<(BB * SS * HH) / 256, 256, 0, stream>>>(x, wemb, Uz, Ur, Uh, bz, br, bh,
                                                         pkV, pkS);
  label_kernel<<<(LL * HH) / 256, 256, 0, stream>>>(lemb, labP, l2);
  gru_kernel  <<<32, 64, 0, stream>>>(Wz, Wr, Wh, bz, br, bh, pkV, pkS, enc, e2);
  dist_kernel <<<BB * (SS / 32) * (LL / 32), 256, 0, stream>>>(enc, e2, labP, l2, inter);
  mlp1_kernel <<<512, 256, 0, stream>>>(inter, W1, b1, hbuf);
  mlp2_kernel <<<512, 256, 0, stream>>>(hbuf, W2, b2, out);
}